// Round 10
// baseline (207.108 us; speedup 1.0000x reference)
//
#include <hip/hip_runtime.h>
#include <hip/hip_bf16.h>
#include <cstdint>
#include <cstddef>

// Problem constants
#define BB 2
#define SS 2048
#define DD 1024
#define HH 16
#define HD 64

typedef __attribute__((ext_vector_type(8))) short bf16x8;
typedef __attribute__((ext_vector_type(4))) float f32x4;
typedef __attribute__((ext_vector_type(16))) float f32x16;

// async global->LDS, 16B per lane, dest = wave-uniform base + lane*16
#define GLL(g, l) __builtin_amdgcn_global_load_lds( \
    (const __attribute__((address_space(1))) void*)(g), \
    (__attribute__((address_space(3))) void*)(l), 16, 0, 0)

// fast RTNE f32->bf16 (inputs guaranteed non-NaN in this problem)
__device__ __forceinline__ short f2bf_fast(float f) {
    uint32_t u = __float_as_uint(f);
    u += 0x7FFF + ((u >> 16) & 1);
    return (short)(u >> 16);
}
__device__ __forceinline__ uint32_t pack_bf2(float a, float b) {
    uint32_t ua = __float_as_uint(a), ub = __float_as_uint(b);
    ua += 0x7FFF + ((ua >> 16) & 1);
    ub += 0x7FFF + ((ub >> 16) & 1);
    return (ua >> 16) | (ub & 0xFFFF0000u);
}
// single-instruction RTNE pack of 2 f32 -> 2 bf16 (bit-identical to pack_bf2)
__device__ __forceinline__ uint32_t cvtpk_bf2(float a, float b) {
    uint32_t r;
    asm("v_cvt_pk_bf16_f32 %0, %1, %2" : "=v"(r) : "v"(a), "v"(b));
    return r;
}
// lane-half exchange: a.hi-lanes <-> b.lo-lanes (v_permlane32_swap_b32 a, b)
__device__ __forceinline__ void pl32swap(uint32_t& a, uint32_t& b) {
    asm("v_permlane32_swap_b32 %0, %1" : "+v"(a), "+v"(b));
}
// 8 fp32 -> 8 bf16 via two float4 loads, packed
__device__ __forceinline__ bf16x8 cvt8(const float* __restrict__ p) {
    float4 a = *(const float4*)p;
    float4 b = *(const float4*)(p + 4);
    union { uint32_t d[4]; bf16x8 v; } r;
    r.d[0] = pack_bf2(a.x, a.y);
    r.d[1] = pack_bf2(a.z, a.w);
    r.d[2] = pack_bf2(b.x, b.y);
    r.d[3] = pack_bf2(b.z, b.w);
    return r.v;
}

// ---------------- fp32 -> bf16 pre-convert (6 tensors, one dispatch) --------
__global__ __launch_bounds__(256) void cvt6_kernel(
    const float* __restrict__ s0, const float* __restrict__ s1,
    const float* __restrict__ s2, const float* __restrict__ s3,
    const float* __restrict__ s4, const float* __restrict__ s5,
    short* __restrict__ d0, short* __restrict__ d1, short* __restrict__ d2,
    short* __restrict__ d3, short* __restrict__ d4, short* __restrict__ d5)
{
    const int id = blockIdx.x * 256 + threadIdx.x;   // 0..1572863
    const float* s; short* d; size_t off;
    if (id < 1048576) {                 // dec / enc, 2^19 chunks each
        int e = id >> 19;
        off = (size_t)(id & 524287) * 8;
        s = e ? s1 : s0;  d = e ? d1 : d0;
    } else {                            // 4 weight tensors, 2^17 chunks each
        int j = id - 1048576;
        int w = j >> 17;
        off = (size_t)(j & 131071) * 8;
        s = (w == 0) ? s2 : (w == 1) ? s3 : (w == 2) ? s4 : s5;
        d = (w == 0) ? d2 : (w == 1) ? d3 : (w == 2) ? d4 : d5;
    }
    bf16x8 r = cvt8(s + off);
    *(uint4*)(d + off) = *(uint4*)&r;
}

// ---------------- fused QKV GEMM: 128x128 tile, BK=64, z selects Q/K/V -----
// (unchanged from R8 — proven: BK=64 + chunk-XOR swizzle, 3 blocks/CU)
template<int BF>
__global__ __launch_bounds__(256, 3) void qkv_gemm_kernel(
    const void* __restrict__ dec, const void* __restrict__ enc,
    const void* __restrict__ Wq, const void* __restrict__ Wk,
    const void* __restrict__ Wv,
    const float* __restrict__ bq, const float* __restrict__ bk,
    const float* __restrict__ bv,
    short* __restrict__ Qo, short* __restrict__ Ko, short* __restrict__ Vo)
{
    __shared__ short As[128 * 64];   // 16 KB, unpadded (global_load_lds)
    __shared__ short Bs[128 * 64];   // 16 KB  (32 KB total -> 3 blocks/CU)

    const int z = blockIdx.z;
    const void* Xv = (z == 0) ? dec : enc;
    const void* Wp_ = (z == 0) ? Wq : (z == 1) ? Wk : Wv;
    const float* bias = (z == 0) ? bq : (z == 1) ? bk : bv;
    short* Yo = (z == 0) ? Qo : (z == 1) ? Ko : Vo;
    const float qs = (z == 0) ? (0.125f * 1.44269504088896f) : 1.0f;

    const int t = threadIdx.x;
    const int lane = t & 63, wv = t >> 6;
    const int lr = lane & 15, quad = lane >> 4;
    const int e7 = lr & 7;                 // read-side swizzle term
    const int wm = wv >> 1, wn = wv & 1;
    const int m0 = blockIdx.y * 128;
    const int n0 = blockIdx.x * 128;
    const int K = DD;

    f32x4 acc[4][4];
    #pragma unroll
    for (int i = 0; i < 4; i++)
        #pragma unroll
        for (int j = 0; j < 4; j++) acc[i][j] = (f32x4){0.f, 0.f, 0.f, 0.f};

    for (int kb = 0; kb < K; kb += 64) {
        __syncthreads();
        if (BF) {
            const short* Xb = (const short*)Xv;
            const short* Wb = (const short*)Wp_;
            #pragma unroll
            for (int c = 0; c < 4; c++) {
                int r0 = wv * 32 + c * 8;           // 8 rows x 128B = 1KB/call
                int r = r0 + (lane >> 3);
                int sc = ((lane & 7) ^ (r & 7)) * 8;
                GLL(Xb + (size_t)(m0 + r) * K + kb + sc, &As[r0 * 64]);
                GLL(Wb + (size_t)(n0 + r) * K + kb + sc, &Bs[r0 * 64]);
            }
        } else {
            const float* Xf = (const float*)Xv;
            const float* Wf = (const float*)Wp_;
            #pragma unroll
            for (int c = 0; c < 4; c++) {
                int id = t + c * 256;               // 1024 chunks of 8
                int r = id >> 3, lc = id & 7;
                int pc = (lc ^ (r & 7)) * 8;
                *(bf16x8*)&As[r * 64 + pc] = cvt8(Xf + (size_t)(m0 + r) * K + kb + lc * 8);
                *(bf16x8*)&Bs[r * 64 + pc] = cvt8(Wf + (size_t)(n0 + r) * K + kb + lc * 8);
            }
        }
        __syncthreads();

        bf16x8 af[4][2], bfr[4][2];
        #pragma unroll
        for (int kk = 0; kk < 2; kk++) {
            int pc = ((kk * 4 + quad) ^ e7) * 8;
            #pragma unroll
            for (int mi = 0; mi < 4; mi++)
                af[mi][kk] = *(const bf16x8*)&As[(wm * 64 + mi * 16 + lr) * 64 + pc];
            #pragma unroll
            for (int ni = 0; ni < 4; ni++)
                bfr[ni][kk] = *(const bf16x8*)&Bs[(wn * 64 + ni * 16 + lr) * 64 + pc];
        }
        #pragma unroll
        for (int kk = 0; kk < 2; kk++)
            #pragma unroll
            for (int mi = 0; mi < 4; mi++)
                #pragma unroll
                for (int ni = 0; ni < 4; ni++)
                    acc[mi][ni] = __builtin_amdgcn_mfma_f32_16x16x32_bf16(
                        af[mi][kk], bfr[ni][kk], acc[mi][ni], 0, 0, 0);
    }

    if (z < 2) {
        #pragma unroll
        for (int ni = 0; ni < 4; ni++) {
            int col = n0 + wn * 64 + ni * 16 + lr;
            int h = col >> 6, hd = col & 63;
            float bvv = bias[col];
            #pragma unroll
            for (int mi = 0; mi < 4; mi++) {
                #pragma unroll
                for (int r2 = 0; r2 < 4; r2++) {
                    int row = m0 + wm * 64 + mi * 16 + quad * 4 + r2;
                    int b = row >> 11, s = row & 2047;
                    float v = (acc[mi][ni][r2] + bvv) * qs;
                    size_t off = ((size_t)(b * HH + h) * SS + s) * HD + hd;
                    Yo[off] = f2bf_fast(v);
                }
            }
        }
    } else {
        // V: r2 indexes consecutive s -> pack 4 bf16 = 8B contiguous stores
        #pragma unroll
        for (int ni = 0; ni < 4; ni++) {
            int col = n0 + wn * 64 + ni * 16 + lr;
            int h = col >> 6, hd = col & 63;
            float bvv = bias[col];
            #pragma unroll
            for (int mi = 0; mi < 4; mi++) {
                int s0 = m0 + wm * 64 + mi * 16 + quad * 4;
                int b = s0 >> 11, s = s0 & 2047;
                union { uint32_t d[2]; } u;
                u.d[0] = pack_bf2(acc[mi][ni][0] + bvv, acc[mi][ni][1] + bvv);
                u.d[1] = pack_bf2(acc[mi][ni][2] + bvv, acc[mi][ni][3] + bvv);
                size_t off = ((size_t)(b * HH + h) * HD + hd) * SS + s;
                *(uint2*)(Yo + off) = *(uint2*)&u;
            }
        }
    }
}

// ---------------- output projection: 64x128 tile (512 blocks = 2/CU) -------
// (reverted to the R8 BK=32 version — BK=64 port regressed in R9)
template<int WBF>
__global__ __launch_bounds__(256, 2) void proj_gemm_kernel(
    const short* __restrict__ X,
    const void* __restrict__ W, const float* __restrict__ bias,
    float* __restrict__ Y)
{
    __shared__ short As[64 * 32];
    __shared__ short Bs[128 * 32];

    const int t = threadIdx.x;
    const int lane = t & 63, wv = t >> 6;
    const int lr = lane & 15, quad = lane >> 4;
    const int wm = wv >> 1, wn = wv & 1;
    const int m0 = blockIdx.y * 64;
    const int n0 = blockIdx.x * 128;
    const int K = DD, N = DD;

    f32x4 acc[2][4];
    #pragma unroll
    for (int i = 0; i < 2; i++)
        #pragma unroll
        for (int j = 0; j < 4; j++) acc[i][j] = (f32x4){0.f, 0.f, 0.f, 0.f};

    for (int kb = 0; kb < K; kb += 32) {
        __syncthreads();
        {   // A: 4KB total, 1 call/wave (16 rows)
            int r0 = wv * 16;
            int r = r0 + (lane >> 2), ch = (lane & 3) * 8;
            GLL(X + (size_t)(m0 + r) * K + kb + ch, &As[r0 * 32]);
        }
        if (WBF) {
            const short* Wb = (const short*)W;
            #pragma unroll
            for (int c = 0; c < 2; c++) {
                int r0 = wv * 32 + c * 16;
                int r = r0 + (lane >> 2), ch = (lane & 3) * 8;
                GLL(Wb + (size_t)(n0 + r) * K + kb + ch, &Bs[r0 * 32]);
            }
        } else {
            const float* Wf = (const float*)W;
            #pragma unroll
            for (int c = 0; c < 2; c++) {
                int id = t + c * 256;
                int r = id >> 2, c8 = (id & 3) * 8;
                *(bf16x8*)&Bs[r * 32 + c8] = cvt8(Wf + (size_t)(n0 + r) * K + kb + c8);
            }
        }
        __syncthreads();

        bf16x8 af[2], bfr[4];
        #pragma unroll
        for (int mi = 0; mi < 2; mi++)
            af[mi] = *(const bf16x8*)&As[(wm * 32 + mi * 16 + lr) * 32 + quad * 8];
        #pragma unroll
        for (int ni = 0; ni < 4; ni++)
            bfr[ni] = *(const bf16x8*)&Bs[(wn * 64 + ni * 16 + lr) * 32 + quad * 8];
        #pragma unroll
        for (int mi = 0; mi < 2; mi++)
            #pragma unroll
            for (int ni = 0; ni < 4; ni++)
                acc[mi][ni] = __builtin_amdgcn_mfma_f32_16x16x32_bf16(
                    af[mi], bfr[ni], acc[mi][ni], 0, 0, 0);
    }

    #pragma unroll
    for (int ni = 0; ni < 4; ni++) {
        int col = n0 + wn * 64 + ni * 16 + lr;
        float bvv = bias[col];
        #pragma unroll
        for (int mi = 0; mi < 2; mi++) {
            #pragma unroll
            for (int r2 = 0; r2 < 4; r2++) {
                int row = m0 + wm * 32 + mi * 16 + quad * 4 + r2;
                Y[(size_t)row * N + col] = acc[mi][ni][r2] + bvv;
            }
        }
    }
}

// ---------------- flash attention: BARRIER-FREE wave-private tiles ----------
// Q,K: [B*H, S, HD] bf16 (Q pre-scaled by 0.125*log2e).  Vt_g: [B*H, HD, S].
// Each wave owns a PRIVATE 16KB LDS region (double-buffered K[32][64] +
// V[64][32], KVBLK=32). Per iter: issue 8 GLLs for tile kt+1 into the
// private back-buffer -> compute tile kt -> wave-local s_waitcnt -> swap.
// ZERO __syncthreads/s_barrier in the kernel: waves de-phase freely (the
// per-tile block barrier coupled all 4 waves' drain+softmax jitter — the
// remaining ~40% no-issue after conflicts/occupancy probes came back null).
// Correctness: GLL dest is wave-uniform-base+lane*16 (private region OK);
// vmcnt/lgkmcnt are wave-local; DS ops retire in-order so the last PV
// MFMA's operand-wait retires all ds_reads before the next stage issues.
// sched_barrier(0) after each waitcnt guards compiler hoisting (rule #18).
// Bank math: K reads = R7's measured-zero-conflict config (g-swizzle);
// V[64][32] (64B rows) with ch^=(row&3) enumerates even over all 8 slots.
__global__ __launch_bounds__(256, 2) void attn_kernel(
    const short* __restrict__ Q,
    const short* __restrict__ Kgl,
    const short* __restrict__ Vt_g,
    short* __restrict__ Y)
{
    __shared__ short smem[32768];   // 64 KB = 4 waves x 16 KB private

    const int t = threadIdx.x;
    const int lane = t & 63, w = t >> 6;
    const int lq = lane & 31, hf = lane >> 5;
    const int gl = (lq & 7) ^ ((lq >> 3) & 3);   // K-read swizzle term
    const int vl = lq & 3;                        // V-read swizzle term

    const int bid = blockIdx.x;
    const int slot = bid >> 3;             // 0..63 within XCD
    const int bh = ((slot >> 4) << 3) + (bid & 7);
    const int qt = slot & 15;
    const int b = bh >> 4, h = bh & 15;

    const int q = qt * 128 + w * 32 + lq;
    const short* Qp = Q + ((size_t)bh * SS + q) * HD;
    bf16x8 qf[4];                      // B-frag j: hd = j*16 + hf*8 + reg
    #pragma unroll
    for (int j = 0; j < 4; j++)
        qf[j] = *(const bf16x8*)(Qp + j * 16 + hf * 8);

    f32x16 o[2];                       // O^T: d = ds*32+(reg&3)+8*(reg>>2)+4*hf
    #pragma unroll
    for (int i = 0; i < 16; i++) { o[0][i] = 0.f; o[1][i] = 0.f; }
    f32x4 vsum = (f32x4){0.f, 0.f, 0.f, 0.f};

    const short* Kb = Kgl + (size_t)bh * SS * HD;
    const short* Vb = Vt_g + (size_t)bh * HD * SS;

    // wave-private region: K bufs at +0/+2048, V bufs at +4096/+6144 (shorts)
    short* wbase = smem + w * 8192;

    // stage 32-key tile kt1 into private buffer nb (8 GLLs, wave-local)
    auto stage = [&](int kt1, int nb) {
        short* Kd = wbase + nb * 2048;          // K[32][64]
        short* Vd = wbase + 4096 + nb * 2048;   // V[64][32]
        #pragma unroll
        for (int c = 0; c < 4; c++) {           // K: 8 rows x 128B per call
            int r = c * 8 + (lane >> 3);
            int g = (r & 7) ^ ((r >> 3) & 3);
            int sc = ((lane & 7) ^ g) * 8;
            GLL(Kb + (size_t)(kt1 * 32 + r) * HD + sc, Kd + c * 8 * 64);
        }
        #pragma unroll
        for (int c = 0; c < 4; c++) {           // V: 16 rows x 64B per call
            int hd = c * 16 + (lane >> 2);
            int sc = ((lane & 3) ^ (hd & 3)) * 8;
            GLL(Vb + (size_t)hd * SS + kt1 * 32 + sc, Vd + c * 16 * 32);
        }
    };

    stage(0, 0);
    asm volatile("s_waitcnt vmcnt(0)" ::: "memory");
    __builtin_amdgcn_sched_barrier(0);

    int cur = 0;
    for (int kt = 0; kt < SS / 32; kt++) {
        if (kt + 1 < SS / 32) stage(kt + 1, cur ^ 1);

        const short* Kc = wbase + cur * 2048;
        const short* Vc = wbase + 4096 + cur * 2048;

        // QK^T for this 32-key tile
        f32x16 sc16 = (f32x16){0.f,0.f,0.f,0.f,0.f,0.f,0.f,0.f,
                               0.f,0.f,0.f,0.f,0.f,0.f,0.f,0.f};
        __builtin_amdgcn_s_setprio(1);
        #pragma unroll
        for (int j = 0; j < 4; j++) {
            bf16x8 kf = *(const bf16x8*)&Kc[lq * 64 + ((j * 2 + hf) ^ gl) * 8];
            sc16 = __builtin_amdgcn_mfma_f32_32x32x16_bf16(kf, qf[j], sc16, 0, 0, 0);
        }
        __builtin_amdgcn_s_setprio(0);

        // softmax -> two PV B-frags
        float ev[16];
        #pragma unroll
        for (int i = 0; i < 16; i++) ev[i] = __builtin_amdgcn_exp2f(sc16[i]);
        #pragma unroll
        for (int r = 0; r < 4; r++)
            vsum += (f32x4){ev[4*r], ev[4*r+1], ev[4*r+2], ev[4*r+3]};
        uint32_t dw[8];
        #pragma unroll
        for (int i = 0; i < 8; i++) dw[i] = cvtpk_bf2(ev[2*i], ev[2*i+1]);
        pl32swap(dw[0], dw[2]); pl32swap(dw[1], dw[3]);
        pl32swap(dw[4], dw[6]); pl32swap(dw[5], dw[7]);
        union { uint32_t u[4]; bf16x8 v; } f0, f1;
        f0.u[0] = dw[0]; f0.u[1] = dw[1]; f0.u[2] = dw[2]; f0.u[3] = dw[3];
        f1.u[0] = dw[4]; f1.u[1] = dw[5]; f1.u[2] = dw[6]; f1.u[3] = dw[7];
        bf16x8 pb0 = f0.v, pb1 = f1.v;

        // O^T += V^T @ P^T  (2 d-subtiles x 2 key-chunks)
        __builtin_amdgcn_s_setprio(1);
        #pragma unroll
        for (int ds = 0; ds < 2; ds++) {
            const short* vrow = &Vc[(ds * 32 + lq) * 32];
            bf16x8 va0 = *(const bf16x8*)&vrow[((0 + hf) ^ vl) * 8];
            o[ds] = __builtin_amdgcn_mfma_f32_32x32x16_bf16(va0, pb0, o[ds], 0, 0, 0);
            bf16x8 va1 = *(const bf16x8*)&vrow[((2 + hf) ^ vl) * 8];
            o[ds] = __builtin_amdgcn_mfma_f32_32x32x16_bf16(va1, pb1, o[ds], 0, 0, 0);
        }
        __builtin_amdgcn_s_setprio(0);

        // wave-local: tile kt+1's GLLs landed; all ds_reads of kt retired
        asm volatile("s_waitcnt vmcnt(0) lgkmcnt(0)" ::: "memory");
        __builtin_amdgcn_sched_barrier(0);
        cur ^= 1;
    }

    float lsum = (vsum[0] + vsum[1]) + (vsum[2] + vsum[3]);
    lsum += __shfl_xor(lsum, 32, 64);
    float inv = 1.0f / lsum;

    short* Yp = Y + ((size_t)b * SS + q) * DD + h * 64 + hf * 4;
    #pragma unroll
    for (int ds = 0; ds < 2; ds++)
        #pragma unroll
        for (int rr = 0; rr < 4; rr++) {
            union { uint32_t d[2]; } u;
            u.d[0] = pack_bf2(o[ds][rr*4+0] * inv, o[ds][rr*4+1] * inv);
            u.d[1] = pack_bf2(o[ds][rr*4+2] * inv, o[ds][rr*4+3] * inv);
            *(uint2*)(Yp + ds * 32 + rr * 8) = *(uint2*)&u;
        }
}

extern "C" void kernel_launch(void* const* d_in, const int* in_sizes, int n_in,
                              void* d_out, int out_size, void* d_ws, size_t ws_size,
                              hipStream_t stream) {
    const float* dec = (const float*)d_in[0];
    const float* enc = (const float*)d_in[1];
    const float* Wq  = (const float*)d_in[2];
    const float* bq  = (const float*)d_in[3];
    const float* Wk  = (const float*)d_in[4];
    const float* bk  = (const float*)d_in[5];
    const float* Wv  = (const float*)d_in[6];
    const float* bv  = (const float*)d_in[7];
    const float* Wp  = (const float*)d_in[8];
    const float* bp  = (const float*)d_in[9];

    const size_t per = (size_t)BB * HH * SS * HD;  // 4,194,304
    const size_t wsz = (size_t)DD * DD;            // 1,048,576
    short* ws = (short*)d_ws;
    short* Qb  = ws;
    short* Kb  = ws + per;
    short* Vtb = ws + 2 * per;
    short* Yb  = ws + 3 * per;

    dim3 qkv_grid(DD / 128, (BB * SS) / 128, 3);   // 768 blocks = 3/CU
    dim3 proj_grid(DD / 128, (BB * SS) / 64);      // 512 blocks = 2/CU
    const int attn_blocks = BB * HH * (SS / 128);  // 512 = 2/CU
    const int cvt_blocks = (2 * 524288 + 4 * 131072) / 256;  // 6144 exact

    const size_t need = (6 * per + 4 * wsz) * sizeof(short);
    if (ws_size >= need) {
        short* decb = ws + 4 * per;
        short* encb = ws + 5 * per;
        short* Wqb  = ws + 6 * per;
        short* Wkb  = Wqb + wsz;
        short* Wvb  = Wqb + 2 * wsz;
        short* Wpb  = Wqb + 3 * wsz;
        cvt6_kernel<<<cvt_blocks, 256, 0, stream>>>(
            dec, enc, Wq, Wk, Wv, Wp, decb, encb, Wqb, Wkb, Wvb, Wpb);
        qkv_gemm_kernel<1><<<qkv_grid, 256, 0, stream>>>(
            decb, encb, Wqb, Wkb, Wvb, bq, bk, bv, Qb, Kb, Vtb);
        attn_kernel<<<attn_blocks, 256, 0, stream>>>(Qb, Kb, Vtb, Yb);
        proj_gemm_kernel<1><<<proj_grid, 256, 0, stream>>>(Yb, Wpb, bp, (float*)d_out);
    } else {
        qkv_gemm_kernel<0><<<qkv_grid, 256, 0, stream>>>(
            dec, enc, Wq, Wk, Wv, bq, bk, bv, Qb, Kb, Vtb);
        attn_kernel<<<attn_blocks, 256, 0, stream>>>(Qb, Kb, Vtb, Yb);
        proj_gemm_kernel<0><<<proj_grid, 256, 0, stream>>>(Yb, Wp, bp, (float*)d_out);
    }
}

// Round 11
// 194.560 us; speedup vs baseline: 1.0645x; 1.0645x over previous
//
#include <hip/hip_runtime.h>
#include <hip/hip_bf16.h>
#include <cstdint>
#include <cstddef>

// Problem constants
#define BB 2
#define SS 2048
#define DD 1024
#define HH 16
#define HD 64

typedef __attribute__((ext_vector_type(8))) short bf16x8;
typedef __attribute__((ext_vector_type(4))) float f32x4;
typedef __attribute__((ext_vector_type(16))) float f32x16;

// async global->LDS, 16B per lane, dest = wave-uniform base + lane*16
#define GLL(g, l) __builtin_amdgcn_global_load_lds( \
    (const __attribute__((address_space(1))) void*)(g), \
    (__attribute__((address_space(3))) void*)(l), 16, 0, 0)

// fast RTNE f32->bf16 (inputs guaranteed non-NaN in this problem)
__device__ __forceinline__ short f2bf_fast(float f) {
    uint32_t u = __float_as_uint(f);
    u += 0x7FFF + ((u >> 16) & 1);
    return (short)(u >> 16);
}
__device__ __forceinline__ uint32_t pack_bf2(float a, float b) {
    uint32_t ua = __float_as_uint(a), ub = __float_as_uint(b);
    ua += 0x7FFF + ((ua >> 16) & 1);
    ub += 0x7FFF + ((ub >> 16) & 1);
    return (ua >> 16) | (ub & 0xFFFF0000u);
}
// single-instruction RTNE pack of 2 f32 -> 2 bf16 (bit-identical to pack_bf2)
__device__ __forceinline__ uint32_t cvtpk_bf2(float a, float b) {
    uint32_t r;
    asm("v_cvt_pk_bf16_f32 %0, %1, %2" : "=v"(r) : "v"(a), "v"(b));
    return r;
}
// lane-half exchange: a.hi-lanes <-> b.lo-lanes (v_permlane32_swap_b32 a, b)
__device__ __forceinline__ void pl32swap(uint32_t& a, uint32_t& b) {
    asm("v_permlane32_swap_b32 %0, %1" : "+v"(a), "+v"(b));
}
// 8 fp32 -> 8 bf16 via two float4 loads, packed
__device__ __forceinline__ bf16x8 cvt8(const float* __restrict__ p) {
    float4 a = *(const float4*)p;
    float4 b = *(const float4*)(p + 4);
    union { uint32_t d[4]; bf16x8 v; } r;
    r.d[0] = pack_bf2(a.x, a.y);
    r.d[1] = pack_bf2(a.z, a.w);
    r.d[2] = pack_bf2(b.x, b.y);
    r.d[3] = pack_bf2(b.z, b.w);
    return r.v;
}

// ---------------- fp32 -> bf16 pre-convert (6 tensors, one dispatch) --------
__global__ __launch_bounds__(256) void cvt6_kernel(
    const float* __restrict__ s0, const float* __restrict__ s1,
    const float* __restrict__ s2, const float* __restrict__ s3,
    const float* __restrict__ s4, const float* __restrict__ s5,
    short* __restrict__ d0, short* __restrict__ d1, short* __restrict__ d2,
    short* __restrict__ d3, short* __restrict__ d4, short* __restrict__ d5)
{
    const int id = blockIdx.x * 256 + threadIdx.x;   // 0..1572863
    const float* s; short* d; size_t off;
    if (id < 1048576) {                 // dec / enc, 2^19 chunks each
        int e = id >> 19;
        off = (size_t)(id & 524287) * 8;
        s = e ? s1 : s0;  d = e ? d1 : d0;
    } else {                            // 4 weight tensors, 2^17 chunks each
        int j = id - 1048576;
        int w = j >> 17;
        off = (size_t)(j & 131071) * 8;
        s = (w == 0) ? s2 : (w == 1) ? s3 : (w == 2) ? s4 : s5;
        d = (w == 0) ? d2 : (w == 1) ? d3 : (w == 2) ? d4 : d5;
    }
    bf16x8 r = cvt8(s + off);
    *(uint4*)(d + off) = *(uint4*)&r;
}

// ---------------- fused QKV GEMM: 128x128 tile, BK=64, z selects Q/K/V -----
// (unchanged from R8 — proven: BK=64 + chunk-XOR swizzle, 3 blocks/CU)
template<int BF>
__global__ __launch_bounds__(256, 3) void qkv_gemm_kernel(
    const void* __restrict__ dec, const void* __restrict__ enc,
    const void* __restrict__ Wq, const void* __restrict__ Wk,
    const void* __restrict__ Wv,
    const float* __restrict__ bq, const float* __restrict__ bk,
    const float* __restrict__ bv,
    short* __restrict__ Qo, short* __restrict__ Ko, short* __restrict__ Vo)
{
    __shared__ short As[128 * 64];   // 16 KB, unpadded (global_load_lds)
    __shared__ short Bs[128 * 64];   // 16 KB  (32 KB total -> 3 blocks/CU)

    const int z = blockIdx.z;
    const void* Xv = (z == 0) ? dec : enc;
    const void* Wp_ = (z == 0) ? Wq : (z == 1) ? Wk : Wv;
    const float* bias = (z == 0) ? bq : (z == 1) ? bk : bv;
    short* Yo = (z == 0) ? Qo : (z == 1) ? Ko : Vo;
    const float qs = (z == 0) ? (0.125f * 1.44269504088896f) : 1.0f;

    const int t = threadIdx.x;
    const int lane = t & 63, wv = t >> 6;
    const int lr = lane & 15, quad = lane >> 4;
    const int e7 = lr & 7;                 // read-side swizzle term
    const int wm = wv >> 1, wn = wv & 1;
    const int m0 = blockIdx.y * 128;
    const int n0 = blockIdx.x * 128;
    const int K = DD;

    f32x4 acc[4][4];
    #pragma unroll
    for (int i = 0; i < 4; i++)
        #pragma unroll
        for (int j = 0; j < 4; j++) acc[i][j] = (f32x4){0.f, 0.f, 0.f, 0.f};

    for (int kb = 0; kb < K; kb += 64) {
        __syncthreads();
        if (BF) {
            const short* Xb = (const short*)Xv;
            const short* Wb = (const short*)Wp_;
            #pragma unroll
            for (int c = 0; c < 4; c++) {
                int r0 = wv * 32 + c * 8;           // 8 rows x 128B = 1KB/call
                int r = r0 + (lane >> 3);
                int sc = ((lane & 7) ^ (r & 7)) * 8;
                GLL(Xb + (size_t)(m0 + r) * K + kb + sc, &As[r0 * 64]);
                GLL(Wb + (size_t)(n0 + r) * K + kb + sc, &Bs[r0 * 64]);
            }
        } else {
            const float* Xf = (const float*)Xv;
            const float* Wf = (const float*)Wp_;
            #pragma unroll
            for (int c = 0; c < 4; c++) {
                int id = t + c * 256;               // 1024 chunks of 8
                int r = id >> 3, lc = id & 7;
                int pc = (lc ^ (r & 7)) * 8;
                *(bf16x8*)&As[r * 64 + pc] = cvt8(Xf + (size_t)(m0 + r) * K + kb + lc * 8);
                *(bf16x8*)&Bs[r * 64 + pc] = cvt8(Wf + (size_t)(n0 + r) * K + kb + lc * 8);
            }
        }
        __syncthreads();

        bf16x8 af[4][2], bfr[4][2];
        #pragma unroll
        for (int kk = 0; kk < 2; kk++) {
            int pc = ((kk * 4 + quad) ^ e7) * 8;
            #pragma unroll
            for (int mi = 0; mi < 4; mi++)
                af[mi][kk] = *(const bf16x8*)&As[(wm * 64 + mi * 16 + lr) * 64 + pc];
            #pragma unroll
            for (int ni = 0; ni < 4; ni++)
                bfr[ni][kk] = *(const bf16x8*)&Bs[(wn * 64 + ni * 16 + lr) * 64 + pc];
        }
        #pragma unroll
        for (int kk = 0; kk < 2; kk++)
            #pragma unroll
            for (int mi = 0; mi < 4; mi++)
                #pragma unroll
                for (int ni = 0; ni < 4; ni++)
                    acc[mi][ni] = __builtin_amdgcn_mfma_f32_16x16x32_bf16(
                        af[mi][kk], bfr[ni][kk], acc[mi][ni], 0, 0, 0);
    }

    if (z < 2) {
        #pragma unroll
        for (int ni = 0; ni < 4; ni++) {
            int col = n0 + wn * 64 + ni * 16 + lr;
            int h = col >> 6, hd = col & 63;
            float bvv = bias[col];
            #pragma unroll
            for (int mi = 0; mi < 4; mi++) {
                #pragma unroll
                for (int r2 = 0; r2 < 4; r2++) {
                    int row = m0 + wm * 64 + mi * 16 + quad * 4 + r2;
                    int b = row >> 11, s = row & 2047;
                    float v = (acc[mi][ni][r2] + bvv) * qs;
                    size_t off = ((size_t)(b * HH + h) * SS + s) * HD + hd;
                    Yo[off] = f2bf_fast(v);
                }
            }
        }
    } else {
        // V: r2 indexes consecutive s -> pack 4 bf16 = 8B contiguous stores
        #pragma unroll
        for (int ni = 0; ni < 4; ni++) {
            int col = n0 + wn * 64 + ni * 16 + lr;
            int h = col >> 6, hd = col & 63;
            float bvv = bias[col];
            #pragma unroll
            for (int mi = 0; mi < 4; mi++) {
                int s0 = m0 + wm * 64 + mi * 16 + quad * 4;
                int b = s0 >> 11, s = s0 & 2047;
                union { uint32_t d[2]; } u;
                u.d[0] = pack_bf2(acc[mi][ni][0] + bvv, acc[mi][ni][1] + bvv);
                u.d[1] = pack_bf2(acc[mi][ni][2] + bvv, acc[mi][ni][3] + bvv);
                size_t off = ((size_t)(b * HH + h) * HD + hd) * SS + s;
                *(uint2*)(Yo + off) = *(uint2*)&u;
            }
        }
    }
}

// ---------------- output projection: 64x128 tile (512 blocks = 2/CU) -------
// (R8 BK=32 version — proven)
template<int WBF>
__global__ __launch_bounds__(256, 2) void proj_gemm_kernel(
    const short* __restrict__ X,
    const void* __restrict__ W, const float* __restrict__ bias,
    float* __restrict__ Y)
{
    __shared__ short As[64 * 32];
    __shared__ short Bs[128 * 32];

    const int t = threadIdx.x;
    const int lane = t & 63, wv = t >> 6;
    const int lr = lane & 15, quad = lane >> 4;
    const int wm = wv >> 1, wn = wv & 1;
    const int m0 = blockIdx.y * 64;
    const int n0 = blockIdx.x * 128;
    const int K = DD, N = DD;

    f32x4 acc[2][4];
    #pragma unroll
    for (int i = 0; i < 2; i++)
        #pragma unroll
        for (int j = 0; j < 4; j++) acc[i][j] = (f32x4){0.f, 0.f, 0.f, 0.f};

    for (int kb = 0; kb < K; kb += 32) {
        __syncthreads();
        {   // A: 4KB total, 1 call/wave (16 rows)
            int r0 = wv * 16;
            int r = r0 + (lane >> 2), ch = (lane & 3) * 8;
            GLL(X + (size_t)(m0 + r) * K + kb + ch, &As[r0 * 32]);
        }
        if (WBF) {
            const short* Wb = (const short*)W;
            #pragma unroll
            for (int c = 0; c < 2; c++) {
                int r0 = wv * 32 + c * 16;
                int r = r0 + (lane >> 2), ch = (lane & 3) * 8;
                GLL(Wb + (size_t)(n0 + r) * K + kb + ch, &Bs[r0 * 32]);
            }
        } else {
            const float* Wf = (const float*)W;
            #pragma unroll
            for (int c = 0; c < 2; c++) {
                int id = t + c * 256;
                int r = id >> 2, c8 = (id & 3) * 8;
                *(bf16x8*)&Bs[r * 32 + c8] = cvt8(Wf + (size_t)(n0 + r) * K + kb + c8);
            }
        }
        __syncthreads();

        bf16x8 af[2], bfr[4];
        #pragma unroll
        for (int mi = 0; mi < 2; mi++)
            af[mi] = *(const bf16x8*)&As[(wm * 32 + mi * 16 + lr) * 32 + quad * 8];
        #pragma unroll
        for (int ni = 0; ni < 4; ni++)
            bfr[ni] = *(const bf16x8*)&Bs[(wn * 64 + ni * 16 + lr) * 32 + quad * 8];
        #pragma unroll
        for (int mi = 0; mi < 2; mi++)
            #pragma unroll
            for (int ni = 0; ni < 4; ni++)
                acc[mi][ni] = __builtin_amdgcn_mfma_f32_16x16x32_bf16(
                    af[mi], bfr[ni], acc[mi][ni], 0, 0, 0);
    }

    #pragma unroll
    for (int ni = 0; ni < 4; ni++) {
        int col = n0 + wn * 64 + ni * 16 + lr;
        float bvv = bias[col];
        #pragma unroll
        for (int mi = 0; mi < 2; mi++) {
            #pragma unroll
            for (int r2 = 0; r2 < 4; r2++) {
                int row = m0 + wm * 32 + mi * 16 + quad * 4 + r2;
                Y[(size_t)row * N + col] = acc[mi][ni][r2] + bvv;
            }
        }
    }
}

// ---------------- flash attention: T15 two-tile P pipeline ------------------
// Q,K: [B*H, S, HD] bf16 (Q pre-scaled by 0.125*log2e).  Vt_g: [B*H, HD, S].
// R6 base (16 x 128-key tiles, 1 barrier/tile, g-swizzle) + softmax(kt)
// OVERLAPPED with PV(kt-1): per iter {stage(kt+1); QK(kt); sched_barrier(0);
// for s: PV4(kt-1, pb_prev[s]) || softmax(s -> pb_cur[s]); barrier}.
// sched_barrier(0) makes sc[4] live across the region boundary -> compiler
// CANNOT re-fuse QK(s)+softmax(s) (R9's silent failure, proven by VGPR=88).
// sched_group_barrier pins {4 ds_read, 4 MFMA, ~32 ALU} per s-group so PV
// MFMA latency is filled by softmax VALU. V is triple-buffered (PV reads
// tile kt-1 while staging kt+1): Ks 32KB + Vt 48KB = 80KB = 2 blocks/CU.
__global__ __launch_bounds__(256, 2) void attn_kernel(
    const short* __restrict__ Q,
    const short* __restrict__ Kgl,
    const short* __restrict__ Vt_g,
    short* __restrict__ Y)
{
    __shared__ short Ks[2][128][64];   // [kt&1][key][hd], g-swizzled chunks
    __shared__ short Vt[3][64][128];   // [kt%3][hd][key], g-swizzled chunks

    const int t = threadIdx.x;
    const int lane = t & 63, w = t >> 6;
    const int lq = lane & 31, hf = lane >> 5;
    const int gl = (lq & 7) ^ ((lq >> 3) & 3);   // g(row) for row = base32 + lq

    const int bid = blockIdx.x;
    const int slot = bid >> 3;             // 0..63 within XCD
    const int bh = ((slot >> 4) << 3) + (bid & 7);
    const int qt = slot & 15;
    const int b = bh >> 4, h = bh & 15;

    const int q = qt * 128 + w * 32 + lq;
    const short* Qp = Q + ((size_t)bh * SS + q) * HD;
    bf16x8 qf[4];                      // B-frag j: hd = j*16 + hf*8 + reg
    #pragma unroll
    for (int j = 0; j < 4; j++)
        qf[j] = *(const bf16x8*)(Qp + j * 16 + hf * 8);

    f32x16 o[2];                       // O^T: d = ds*32+(reg&3)+8*(reg>>2)+4*hf
    #pragma unroll
    for (int i = 0; i < 16; i++) { o[0][i] = 0.f; o[1][i] = 0.f; }
    f32x4 vsum = (f32x4){0.f, 0.f, 0.f, 0.f};

    const short* Kb = Kgl + (size_t)bh * SS * HD;
    const short* Vb = Vt_g + (size_t)bh * HD * SS;

    // stage tile kt1 into Ks[kt1&1], Vt[kt1%3]; source pre-swizzled by g(row)
    auto stage = [&](int kt1) {
        short* Kd = &Ks[kt1 & 1][0][0];
        short* Vd = &Vt[kt1 % 3][0][0];
        #pragma unroll
        for (int c = 0; c < 4; c++) {
            int r0 = w * 32 + c * 8;
            int r  = r0 + (lane >> 3);
            int g  = (r & 7) ^ ((r >> 3) & 3);
            int sc = ((lane & 7) ^ g) * 8;
            GLL(Kb + (size_t)(kt1 * 128 + r) * 64 + sc, Kd + r0 * 64);
        }
        #pragma unroll
        for (int c = 0; c < 4; c++) {
            int h0 = w * 16 + c * 4;
            int hd = h0 + (lane >> 4);
            int g  = (hd & 7) ^ ((hd >> 3) & 3);
            int s16 = (lane & 15) ^ g;
            GLL(Vb + (size_t)hd * SS + kt1 * 128 + s16 * 8, Vd + h0 * 128);
        }
    };

    // QK^T for tile kt -> sc[4]; j-outer/s-inner (4 independent chains)
    auto qk = [&](int kt, f32x16 (&sc)[4]) {
        const short (*Kc)[64] = Ks[kt & 1];
        __builtin_amdgcn_s_setprio(1);
        #pragma unroll
        for (int j = 0; j < 4; j++)
            #pragma unroll
            for (int s = 0; s < 4; s++) {
                bf16x8 kf = *(const bf16x8*)&Kc[s * 32 + lq][((j * 2 + hf) ^ gl) * 8];
                sc[s] = __builtin_amdgcn_mfma_f32_32x32x16_bf16(kf, qf[j], sc[s], 0, 0, 0);
            }
        __builtin_amdgcn_s_setprio(0);
    };

    // softmax of one 32-key subtile -> two PV B-frags
    auto sm = [&](const f32x16& scs, bf16x8& p0, bf16x8& p1) {
        float ev[16];
        #pragma unroll
        for (int i = 0; i < 16; i++) ev[i] = __builtin_amdgcn_exp2f(scs[i]);
        #pragma unroll
        for (int r = 0; r < 4; r++)
            vsum += (f32x4){ev[4*r], ev[4*r+1], ev[4*r+2], ev[4*r+3]};
        uint32_t dw[8];
        #pragma unroll
        for (int i = 0; i < 8; i++) dw[i] = cvtpk_bf2(ev[2*i], ev[2*i+1]);
        pl32swap(dw[0], dw[2]); pl32swap(dw[1], dw[3]);
        pl32swap(dw[4], dw[6]); pl32swap(dw[5], dw[7]);
        union { uint32_t u[4]; bf16x8 v; } f0, f1;
        f0.u[0] = dw[0]; f0.u[1] = dw[1]; f0.u[2] = dw[2]; f0.u[3] = dw[3];
        f1.u[0] = dw[4]; f1.u[1] = dw[5]; f1.u[2] = dw[6]; f1.u[3] = dw[7];
        p0 = f0.v; p1 = f1.v;
    };

    // PV for one key-subtile s of a tile whose V lives at Vc
    auto pv4 = [&](const short* Vc, int s, bf16x8 p0, bf16x8 p1) {
        #pragma unroll
        for (int ds = 0; ds < 2; ds++) {
            const short* vrow = Vc + (ds * 32 + lq) * 128;
            bf16x8 va0 = *(const bf16x8*)&vrow[((s * 4 + 0 + hf) ^ gl) * 8];
            o[ds] = __builtin_amdgcn_mfma_f32_32x32x16_bf16(va0, p0, o[ds], 0, 0, 0);
            bf16x8 va1 = *(const bf16x8*)&vrow[((s * 4 + 2 + hf) ^ gl) * 8];
            o[ds] = __builtin_amdgcn_mfma_f32_32x32x16_bf16(va1, p1, o[ds], 0, 0, 0);
        }
    };

    bf16x8 pbA[4][2], pbB[4][2];

    // main-loop body: tile kt; consumes pbp (tile kt-1's P), produces pbc
    auto body = [&](int kt, bf16x8 (&pbp)[4][2], bf16x8 (&pbc)[4][2]) {
        if (kt + 1 < 16) stage(kt + 1);
        f32x16 sc[4];
        #pragma unroll
        for (int s = 0; s < 4; s++)
            #pragma unroll
            for (int i = 0; i < 16; i++) sc[s][i] = 0.f;
        qk(kt, sc);
        __builtin_amdgcn_sched_barrier(0);   // sc[4] stays live; phases split
        const short* Vprev = &Vt[(kt + 2) % 3][0][0];   // == (kt-1)%3
        __builtin_amdgcn_s_setprio(1);
        #pragma unroll
        for (int s = 0; s < 4; s++) {
            pv4(Vprev, s, pbp[s][0], pbp[s][1]);
            sm(sc[s], pbc[s][0], pbc[s][1]);
            __builtin_amdgcn_sched_group_barrier(0x100, 4, 0);  // 4 ds_read
            __builtin_amdgcn_sched_group_barrier(0x008, 4, 0);  // 4 MFMA
            __builtin_amdgcn_sched_group_barrier(0x001, 32, 0); // ALU cluster
        }
        __builtin_amdgcn_s_setprio(0);
        __syncthreads();
    };

    stage(0);
    __syncthreads();

    {   // prologue: tile 0 (no PV yet)
        stage(1);
        f32x16 sc[4];
        #pragma unroll
        for (int s = 0; s < 4; s++)
            #pragma unroll
            for (int i = 0; i < 16; i++) sc[s][i] = 0.f;
        qk(0, sc);
        __builtin_amdgcn_sched_barrier(0);
        #pragma unroll
        for (int s = 0; s < 4; s++) sm(sc[s], pbA[s][0], pbA[s][1]);
        __syncthreads();
    }

    for (int kt = 1; kt <= 13; kt += 2) {
        body(kt, pbA, pbB);
        body(kt + 1, pbB, pbA);
    }
    body(15, pbA, pbB);

    // epilogue: PV(15) from Vt[15%3 = 0]
    __builtin_amdgcn_s_setprio(1);
    #pragma unroll
    for (int s = 0; s < 4; s++) pv4(&Vt[0][0][0], s, pbB[s][0], pbB[s][1]);
    __builtin_amdgcn_s_setprio(0);

    float lsum = (vsum[0] + vsum[1]) + (vsum[2] + vsum[3]);
    lsum += __shfl_xor(lsum, 32, 64);
    float inv = 1.0f / lsum;

    short* Yp = Y + ((size_t)b * SS + q) * DD + h * 64 + hf * 4;
    #pragma unroll
    for (int ds = 0; ds < 2; ds++)
        #pragma unroll
        for (int rr = 0; rr < 4; rr++) {
            union { uint32_t d[2]; } u;
            u.d[0] = pack_bf2(o[ds][rr*4+0] * inv, o[ds][rr*4+1] * inv);
            u.d[1] = pack_bf2(o[ds][rr*4+2] * inv, o[ds][rr*4+3] * inv);
            *(uint2*)(Yp + ds * 32 + rr * 8) = *(uint2*)&u;
        }
}

extern "C" void kernel_launch(void* const* d_in, const int* in_sizes, int n_in,
                              void* d_out, int out_size, void* d_ws, size_t ws_size,
                              hipStream_t stream) {
    const float* dec = (const float*)d_in[0];
    const float* enc = (const float*)d_in[1];
    const float* Wq  = (const float*)d_in[2];
    const float* bq  = (const float*)d_in[3];
    const float* Wk  = (const float*)d_in[4];
    const float* bk  = (const float*)d_in[5];
    const float* Wv  = (const float*)d_in[6];
    const float* bv  = (const float*)d_in[7];
    const float* Wp  = (const float*)d_in[8];
    const float* bp  = (const float*)d_in[9];

    const size_t per = (size_t)BB * HH * SS * HD;  // 4,194,304
    const size_t wsz = (size_t)DD * DD;            // 1,048,576
    short* ws = (short*)d_ws;
    short* Qb  = ws;
    short* Kb  = ws + per;
    short* Vtb = ws + 2 * per;
    short* Yb  = ws + 3 * per;

    dim3 qkv_grid(DD / 128, (BB * SS) / 128, 3);   // 768 blocks = 3/CU
    dim3 proj_grid(DD / 128, (BB * SS) / 64);      // 512 blocks = 2/CU
    const int attn_blocks = BB * HH * (SS / 128);  // 512 = 2/CU
    const int cvt_blocks = (2 * 524288 + 4 * 131072) / 256;  // 6144 exact

    const size_t need = (6 * per + 4 * wsz) * sizeof(short);
    if (ws_size >= need) {
        short* decb = ws + 4 * per;
        short* encb = ws + 5 * per;
        short* Wqb  = ws + 6 * per;
        short* Wkb  = Wqb + wsz;
        short* Wvb  = Wqb + 2 * wsz;
        short* Wpb  = Wqb + 3 * wsz;
        cvt6_kernel<<<cvt_blocks, 256, 0, stream>>>(
            dec, enc, Wq, Wk, Wv, Wp, decb, encb, Wqb, Wkb, Wvb, Wpb);
        qkv_gemm_kernel<1><<<qkv_grid, 256, 0, stream>>>(
            decb, encb, Wqb, Wkb, Wvb, bq, bk, bv, Qb, Kb, Vtb);
        attn_kernel<<<attn_blocks, 256, 0, stream>>>(Qb, Kb, Vtb, Yb);
        proj_gemm_kernel<1><<<proj_grid, 256, 0, stream>>>(Yb, Wpb, bp, (float*)d_out);
    } else {
        qkv_gemm_kernel<0><<<qkv_grid, 256, 0, stream>>>(
            dec, enc, Wq, Wk, Wv, bq, bk, bv, Qb, Kb, Vtb);
        attn_kernel<<<attn_blocks, 256, 0, stream>>>(Qb, Kb, Vtb, Yb);
        proj_gemm_kernel<0><<<proj_grid, 256, 0, stream>>>(Yb, Wp, bp, (float*)d_out);
    }
}